// Round 4
// baseline (2093.391 us; speedup 1.0000x reference)
//
#include <hip/hip_runtime.h>
#include <stdint.h>

typedef unsigned short u16;
typedef __bf16 bf16x8 __attribute__((ext_vector_type(8)));
typedef float f32x4 __attribute__((ext_vector_type(4)));

#define NLAYER 6
#define DM 768
#define NH 12
#define FD 3072
#define NCLS 10
#define BATCH 8
#define SEQ 1024
#define NTOK (BATCH*SEQ)
#define PST 72   // padded stride for attention P strip

__device__ __forceinline__ u16 f2bf(float f) {
  union { float f; unsigned u; } v; v.f = f;
  unsigned u = v.u;
  return (u16)((u + 0x7fffu + ((u >> 16) & 1u)) >> 16);
}

__device__ __forceinline__ void async16(const void* g, void* l) {
  __builtin_amdgcn_global_load_lds(
      (__attribute__((address_space(1))) void*)(void*)g,
      (__attribute__((address_space(3))) void*)l, 16, 0, 0);
}

// ---------------- pack weights fp32 [K][N] -> MFMA B-fragment-major bf16 ----------------
// dst frag layout: [(ntOff+nt)*K32 + kc][lane][8] ; lane: n = nt*16+(lane&15), k = kc*32+(lane>>4)*8+j
__global__ __launch_bounds__(256) void pack_weights(
    const float* __restrict__ src, u16* __restrict__ dst,
    int K, int N, long srcLS, long dstLS, int ntOff, int ntCount)
{
  int z = blockIdx.z;
  int K32 = K >> 5;
  int fid = blockIdx.x * 4 + (threadIdx.x >> 6);
  int ntL = fid / K32, kc = fid - ntL * K32;
  if (ntL >= ntCount) return;
  int lane = threadIdx.x & 63;
  int l15 = lane & 15, quad = lane >> 4;
  int n = ntL * 16 + l15;
  const float* s = src + (long)z * srcLS + (long)(kc * 32 + quad * 8) * N + n;
  unsigned pk[4];
  #pragma unroll
  for (int j = 0; j < 4; j++) {
    u16 a = f2bf(s[(2 * j) * (long)N]);
    u16 b = f2bf(s[(2 * j + 1) * (long)N]);
    pk[j] = (unsigned)a | ((unsigned)b << 16);
  }
  u16* d = dst + (long)z * dstLS + ((long)(ntOff + ntL) * K32 + kc) * 512 + lane * 8;
  *(uint4*)d = *(uint4*)pk;
}

// ---------------- concat q/k/v biases into [NLAYER][2304] ----------------
__global__ void concat_bias(const float* __restrict__ bq, const float* __restrict__ bk,
                            const float* __restrict__ bv, float* __restrict__ qkvb)
{
  int i = blockIdx.x * 256 + threadIdx.x;
  if (i >= NLAYER * 2304) return;
  int layer = i / 2304, c = i % 2304;
  float v;
  if (c < 768) v = bq[layer * 768 + c];
  else if (c < 1536) v = bk[layer * 768 + c - 768];
  else v = bv[layer * 768 + c - 1536];
  qkvb[i] = v;
}

// ---------------- embedding + sinusoidal PE -> x fp32 + x bf16 ----------------
__global__ __launch_bounds__(256) void embed_kernel(
    const int* __restrict__ ids, const float* __restrict__ emb,
    float* __restrict__ x, u16* __restrict__ xb)
{
  int e = (blockIdx.x * 256 + threadIdx.x) * 4;
  int d = e % DM;
  int tok = e / DM;
  int l = tok % SEQ;
  int id = ids[tok];
  float4 em = *(const float4*)(emb + (long)id * DM + d);
  const float cexp = -9.210340371976184f / 768.f;   // -ln(10000)/D
  float div0 = __expf((float)d * cexp);
  float div1 = __expf((float)(d + 2) * cexp);
  float a0 = (float)l * div0, a1 = (float)l * div1;
  em.x += sinf(a0); em.y += cosf(a0);
  em.z += sinf(a1); em.w += cosf(a1);
  *(float4*)(x + e) = em;
  uint2 pk;
  pk.x = f2bf(em.x) | ((unsigned)f2bf(em.y) << 16);
  pk.y = f2bf(em.z) | ((unsigned)f2bf(em.w) << 16);
  *(uint2*)(xb + e) = pk;
}

// ---------------- bf16 MFMA GEMM, B from packed global fragments ----------------
// TM x 128 block tile, 2x2 waves (wave tile TM/2 x 64). A staged in LDS (swizzled,
// async16); B read per-wave as dwordx4 fragments with 1-iter register prefetch.
template<int TM>
__global__ __launch_bounds__(256) void gemm_pk(
    const u16* __restrict__ A, const u16* __restrict__ WP,
    const float* __restrict__ bias,
    float* __restrict__ Cf, u16* __restrict__ Cb, u16* __restrict__ VTout,
    int N, int K, int relu)
{
  constexpr int MI  = TM / 32;           // A fragments per wave
  constexpr int ACH = TM / 8;            // 1KB staging chunks
  constexpr int ASZ = (TM == 128) ? 9216 : TM * 64;  // extra room for epilogue strips
  __shared__ __align__(16) u16 As[ASZ];
  int tid = threadIdx.x;
  int wave = tid >> 6, lane = tid & 63;
  int wm = (wave >> 1) * (TM / 2);
  int wn = (wave & 1) * 64;
  int l15 = lane & 15, quad = lane >> 4;
  long mBase = (long)blockIdx.x * TM;
  long nBase = (long)blockIdx.y * 128;
  int K32 = K >> 5;
  int r8 = lane >> 3;
  int g8 = ((lane & 7) ^ r8) * 8;

  const u16* gsrc[ACH / 4];
  u16* ldst[ACH / 4];
  #pragma unroll
  for (int idx = 0; idx < ACH / 4; idx++) {
    int c = wave + idx * 4;
    gsrc[idx] = A + (mBase + c * 8 + r8) * (long)K + g8;
    ldst[idx] = As + c * 512;
  }
  int sw = l15 & 7;
  int aoff[2];
  #pragma unroll
  for (int kc = 0; kc < 2; kc++)
    aoff[kc] = (wm + l15) * 64 + 8 * ((kc * 4 + quad) ^ sw);

  const u16* bpp = WP + ((long)(nBase >> 4) + (wn >> 4)) * K32 * 512 + lane * 8;
  uint4 bnx[2][4];
  #pragma unroll
  for (int kc = 0; kc < 2; kc++)
    #pragma unroll
    for (int j = 0; j < 4; j++)
      bnx[kc][j] = *(const uint4*)(bpp + ((long)j * K32 + kc) * 512);

  f32x4 acc[MI][4] = {};

  for (int k0 = 0; k0 < K; k0 += 64) {
    __syncthreads();
    #pragma unroll
    for (int idx = 0; idx < ACH / 4; idx++)
      async16(gsrc[idx] + k0, ldst[idx]);
    __syncthreads();

    uint4 bcur[2][4];
    #pragma unroll
    for (int kc = 0; kc < 2; kc++)
      #pragma unroll
      for (int j = 0; j < 4; j++)
        bcur[kc][j] = bnx[kc][j];
    if (k0 + 64 < K) {
      int nch = (k0 >> 5) + 2;
      #pragma unroll
      for (int kc = 0; kc < 2; kc++)
        #pragma unroll
        for (int j = 0; j < 4; j++)
          bnx[kc][j] = *(const uint4*)(bpp + ((long)j * K32 + nch + kc) * 512);
    }
    #pragma unroll
    for (int kc = 0; kc < 2; kc++) {
      bf16x8 aF[MI];
      #pragma unroll
      for (int i = 0; i < MI; i++) aF[i] = *(const bf16x8*)(As + aoff[kc] + i * 1024);
      #pragma unroll
      for (int i = 0; i < MI; i++)
        #pragma unroll
        for (int j = 0; j < 4; j++) {
          bf16x8 bb = *(bf16x8*)&bcur[kc][j];
          acc[i][j] = __builtin_amdgcn_mfma_f32_16x16x32_bf16(aF[i], bb, acc[i][j], 0, 0, 0);
        }
    }
  }

  if (VTout != nullptr && nBase >= 1536) {
    // V block of the QKV GEMM: store transposed to VT[bh][dk][seq]
    #pragma unroll
    for (int j = 0; j < 4; j++) {
      long gn = nBase + wn + j * 16 + l15;
      float bv = bias[gn];
      int h = ((int)gn - 1536) >> 6, dk = (int)gn & 63;
      #pragma unroll
      for (int i = 0; i < MI; i++) {
        long gm0 = mBase + wm + i * 16 + quad * 4;
        int bb = (int)(gm0 >> 10), seq = (int)(gm0 & 1023);
        u16* dst = VTout + (((long)(bb * NH + h) * 64 + dk) << 10) + seq;
        uint2 pk;
        pk.x = f2bf(acc[i][j][0] + bv) | ((unsigned)f2bf(acc[i][j][1] + bv) << 16);
        pk.y = f2bf(acc[i][j][2] + bv) | ((unsigned)f2bf(acc[i][j][3] + bv) << 16);
        *(uint2*)dst = pk;
      }
    }
  } else if (Cb != nullptr) {
    if constexpr (TM == 128) {
      // bf16 out via per-wave LDS strip -> coalesced uint4 row stores
      __syncthreads();                       // done with As staging reads
      u16* ep = As + wave * 2304;            // 32 rows x stride 72
      float bvj[4];
      #pragma unroll
      for (int j = 0; j < 4; j++) bvj[j] = bias[nBase + wn + j * 16 + l15];
      #pragma unroll
      for (int h = 0; h < 2; h++) {
        #pragma unroll
        for (int ii = 0; ii < 2; ii++) {
          int i = 2 * h + ii;
          #pragma unroll
          for (int j = 0; j < 4; j++)
            #pragma unroll
            for (int r = 0; r < 4; r++) {
              float v = acc[i][j][r] + bvj[j];
              if (relu) v = fmaxf(v, 0.f);
              ep[(ii * 16 + quad * 4 + r) * 72 + j * 16 + l15] = f2bf(v);
            }
        }
        #pragma unroll
        for (int rr = 0; rr < 2; rr++) {
          int row = (lane >> 2) + rr * 16;
          int c = (lane & 3) * 16;
          uint4 d0 = *(const uint4*)&ep[row * 72 + c];
          uint4 d1 = *(const uint4*)&ep[row * 72 + c + 8];
          long gm = mBase + wm + h * 32 + row;
          u16* dst = Cb + gm * (long)N + nBase + wn + c;
          *(uint4*)dst = d0;
          *(uint4*)(dst + 8) = d1;
        }
      }
    }
  } else {
    // fp32 direct stores (dword per lane, 64B segments)
    #pragma unroll
    for (int j = 0; j < 4; j++) {
      long gn = nBase + wn + j * 16 + l15;
      float bv = bias[gn];
      #pragma unroll
      for (int i = 0; i < MI; i++) {
        long gm0 = mBase + wm + i * 16 + quad * 4;
        #pragma unroll
        for (int r = 0; r < 4; r++) {
          float v = acc[i][j][r] + bv;
          if (relu) v = fmaxf(v, 0.f);
          Cf[(gm0 + r) * (long)N + gn] = v;
        }
      }
    }
  }
}

// ---------------- MFMA flash attention, fixed-max softmax, async swizzled staging ----------------
__global__ __launch_bounds__(256) void attention_mfma(
    const u16* __restrict__ qkvb, const int* __restrict__ mask,
    const u16* __restrict__ vtg, u16* __restrict__ ctxb)
{
  __shared__ __align__(16) u16 Kb[64 * 64];
  __shared__ __align__(16) u16 Vt[64 * 64];
  __shared__ __align__(16) u16 Pl[4][16 * PST];
  __shared__ float negs[64];
  int tid = threadIdx.x;
  int wave = tid >> 6, lane = tid & 63;
  int l15 = lane & 15, quad = lane >> 4;
  int qt = blockIdx.x, bh = blockIdx.y;
  int b = bh / NH, h = bh - b * NH;
  long qtok = (long)b * SEQ + qt * 64;

  bf16x8 aQ[2];
  {
    const u16* qp = qkvb + (qtok + wave * 16 + l15) * 2304 + h * 64 + quad * 8;
    aQ[0] = *(const bf16x8*)qp;
    aQ[1] = *(const bf16x8*)(qp + 32);
  }
  f32x4 oacc[4] = {};
  float lrow[4] = {0.f, 0.f, 0.f, 0.f};

  int r8 = lane >> 3;
  int g8 = ((lane & 7) ^ r8) * 8;
  int ck0 = wave * 2, ck1 = wave * 2 + 1;
  const u16* kg0 = qkvb + ((long)b * SEQ + ck0 * 8 + r8) * 2304 + 768 + h * 64 + g8;
  const u16* kg1 = qkvb + ((long)b * SEQ + ck1 * 8 + r8) * 2304 + 768 + h * 64 + g8;
  const u16* vg0 = vtg + ((long)bh * 64 + ck0 * 8 + r8) * SEQ + g8;
  const u16* vg1 = vtg + ((long)bh * 64 + ck1 * 8 + r8) * SEQ + g8;
  int sw = l15 & 7;
  int soff[2], aoffP[2];
  #pragma unroll
  for (int kc = 0; kc < 2; kc++) {
    soff[kc]  = l15 * 64 + 8 * ((kc * 4 + quad) ^ sw);
    aoffP[kc] = l15 * PST + kc * 32 + quad * 8;
  }
  u16* pw = &Pl[wave][0];

  for (int kt = 0; kt < 16; kt++) {
    __syncthreads();
    async16(kg0 + (long)kt * 64 * 2304, Kb + ck0 * 512);
    async16(kg1 + (long)kt * 64 * 2304, Kb + ck1 * 512);
    async16(vg0 + kt * 64, Vt + ck0 * 512);
    async16(vg1 + kt * 64, Vt + ck1 * 512);
    if (tid < 64) negs[tid] = (mask[(long)b * SEQ + kt * 64 + tid] == 0) ? -1e9f : 0.f;
    __syncthreads();

    f32x4 sa[4] = {};
    #pragma unroll
    for (int kc = 0; kc < 2; kc++)
      #pragma unroll
      for (int n = 0; n < 4; n++) {
        bf16x8 bk = *(const bf16x8*)&Kb[n * 1024 + soff[kc]];
        sa[n] = __builtin_amdgcn_mfma_f32_16x16x32_bf16(aQ[kc], bk, sa[n], 0, 0, 0);
      }
    float ng[4];
    #pragma unroll
    for (int n = 0; n < 4; n++) ng[n] = negs[n * 16 + l15];
    #pragma unroll
    for (int n = 0; n < 4; n++)
      #pragma unroll
      for (int r = 0; r < 4; r++) {
        float s = fminf(sa[n][r] * 0.125f + ng[n], 60.f);
        float p = __expf(s);
        lrow[r] += p;
        pw[(quad * 4 + r) * PST + n * 16 + l15] = f2bf(p);
      }
    #pragma unroll
    for (int kc = 0; kc < 2; kc++) {
      bf16x8 ap = *(const bf16x8*)&pw[aoffP[kc]];
      #pragma unroll
      for (int d = 0; d < 4; d++) {
        bf16x8 bv = *(const bf16x8*)&Vt[d * 1024 + soff[kc]];
        oacc[d] = __builtin_amdgcn_mfma_f32_16x16x32_bf16(ap, bv, oacc[d], 0, 0, 0);
      }
    }
  }

  #pragma unroll
  for (int r = 0; r < 4; r++) {
    lrow[r] += __shfl_xor(lrow[r], 1, 64);
    lrow[r] += __shfl_xor(lrow[r], 2, 64);
    lrow[r] += __shfl_xor(lrow[r], 4, 64);
    lrow[r] += __shfl_xor(lrow[r], 8, 64);
  }
  float inv[4];
  #pragma unroll
  for (int r = 0; r < 4; r++) inv[r] = 1.f / lrow[r];
  #pragma unroll
  for (int d = 0; d < 4; d++)
    #pragma unroll
    for (int r = 0; r < 4; r++)
      pw[(quad * 4 + r) * PST + d * 16 + l15] = f2bf(oacc[d][r] * inv[r]);
  int orow = lane >> 2, ocol = (lane & 3) * 16;
  u16* og = ctxb + (qtok + wave * 16 + orow) * DM + h * 64 + ocol;
  *(uint4*)og       = *(const uint4*)&pw[orow * PST + ocol];
  *(uint4*)(og + 8) = *(const uint4*)&pw[orow * PST + ocol + 8];
}

// ---------------- fused residual + layernorm ----------------
__global__ __launch_bounds__(64) void ln_residual(
    const float* __restrict__ x, const float* __restrict__ y,
    const float* __restrict__ g, const float* __restrict__ b,
    float* __restrict__ xout, u16* __restrict__ xbout)
{
  long row = blockIdx.x;
  int t = threadIdx.x;
  const float* xr = x + row * DM;
  const float* yr = y + row * DM;
  float v[12];
  float sum = 0.f, sq = 0.f;
  #pragma unroll
  for (int j = 0; j < 3; j++) {
    int d = j * 256 + t * 4;
    float4 a = *(const float4*)(xr + d);
    float4 c = *(const float4*)(yr + d);
    float z0 = a.x + c.x, z1 = a.y + c.y, z2 = a.z + c.z, z3 = a.w + c.w;
    v[j*4+0] = z0; v[j*4+1] = z1; v[j*4+2] = z2; v[j*4+3] = z3;
    sum += z0 + z1 + z2 + z3;
    sq  += z0*z0 + z1*z1 + z2*z2 + z3*z3;
  }
  #pragma unroll
  for (int m = 1; m < 64; m <<= 1) {
    sum += __shfl_xor(sum, m, 64);
    sq  += __shfl_xor(sq,  m, 64);
  }
  float mu = sum * (1.f / 768.f);
  float var = sq * (1.f / 768.f) - mu * mu;
  float rstd = rsqrtf(var + 1e-5f);
  #pragma unroll
  for (int j = 0; j < 3; j++) {
    int d = j * 256 + t * 4;
    float4 gg = *(const float4*)(g + d);
    float4 bb = *(const float4*)(b + d);
    float z0 = (v[j*4+0] - mu) * rstd * gg.x + bb.x;
    float z1 = (v[j*4+1] - mu) * rstd * gg.y + bb.y;
    float z2 = (v[j*4+2] - mu) * rstd * gg.z + bb.z;
    float z3 = (v[j*4+3] - mu) * rstd * gg.w + bb.w;
    float4 fz; fz.x = z0; fz.y = z1; fz.z = z2; fz.w = z3;
    *(float4*)(xout + row * DM + d) = fz;
    uint2 pk;
    pk.x = f2bf(z0) | ((unsigned)f2bf(z1) << 16);
    pk.y = f2bf(z2) | ((unsigned)f2bf(z3) << 16);
    *(uint2*)(xbout + row * DM + d) = pk;
  }
}

// ---------------- classifier ----------------
__global__ __launch_bounds__(64) void classifier_kernel(
    const float* __restrict__ x, const float* __restrict__ w,
    const float* __restrict__ bias, float* __restrict__ out)
{
  int bc = blockIdx.x;
  int b = bc / NCLS, c = bc % NCLS;
  const float* xr = x + (long)b * SEQ * DM;
  float sum = 0.f;
  for (int d = threadIdx.x; d < DM; d += 64)
    sum += xr[d] * w[d * NCLS + c];
  #pragma unroll
  for (int m = 1; m < 64; m <<= 1) sum += __shfl_xor(sum, m, 64);
  if (threadIdx.x == 0) out[bc] = sum + bias[c];
}

extern "C" void kernel_launch(void* const* d_in, const int* in_sizes, int n_in,
                              void* d_out, int out_size, void* d_ws, size_t ws_size,
                              hipStream_t stream)
{
  const int*   ids  = (const int*)d_in[0];
  const int*   mask = (const int*)d_in[1];
  const float* emb  = (const float*)d_in[2];
  const float* wq   = (const float*)d_in[3];
  const float* bq   = (const float*)d_in[4];
  const float* wk   = (const float*)d_in[5];
  const float* bk   = (const float*)d_in[6];
  const float* wv   = (const float*)d_in[7];
  const float* bv   = (const float*)d_in[8];
  const float* wo   = (const float*)d_in[9];
  const float* bo   = (const float*)d_in[10];
  const float* ln1g = (const float*)d_in[11];
  const float* ln1b = (const float*)d_in[12];
  const float* w1   = (const float*)d_in[13];
  const float* b1   = (const float*)d_in[14];
  const float* w2   = (const float*)d_in[15];
  const float* b2   = (const float*)d_in[16];
  const float* ln2g = (const float*)d_in[17];
  const float* ln2b = (const float*)d_in[18];
  const float* clsw = (const float*)d_in[19];
  const float* clsb = (const float*)d_in[20];

  char* ws = (char*)d_ws;
  size_t off = 0;
  auto alloc = [&](size_t bytes) -> void* {
    void* p = ws + off;
    off += (bytes + 255) & ~(size_t)255;
    return p;
  };
  float* X      = (float*)alloc((size_t)NTOK * DM * 4);
  u16*   XB     = (u16*)  alloc((size_t)NTOK * DM * 2);
  u16*   QKVB16 = (u16*)  alloc((size_t)NTOK * 2304 * 2);
  u16*   VT     = (u16*)  alloc((size_t)96 * 64 * SEQ * 2);
  u16*   CTXB   = (u16*)  alloc((size_t)NTOK * DM * 2);
  u16*   H1B    = (u16*)  alloc((size_t)NTOK * FD * 2);
  float* SCR    = (float*)alloc((size_t)NTOK * DM * 4);
  u16*   WQKV_P = (u16*)  alloc((size_t)NLAYER * 144 * 24 * 512 * 2);
  u16*   WO_P   = (u16*)  alloc((size_t)NLAYER * 48 * 24 * 512 * 2);
  u16*   W1_P   = (u16*)  alloc((size_t)NLAYER * 192 * 24 * 512 * 2);
  u16*   W2_P   = (u16*)  alloc((size_t)NLAYER * 48 * 96 * 512 * 2);
  float* QKVB   = (float*)alloc((size_t)NLAYER * 2304 * 4);

  const long LSW = 768L * 768;   // per-layer fp32 weight strides
  pack_weights<<<dim3(288, 1, 6), 256, 0, stream>>>(wq, WQKV_P, 768, 768, LSW, 144L*24*512, 0, 48);
  pack_weights<<<dim3(288, 1, 6), 256, 0, stream>>>(wk, WQKV_P, 768, 768, LSW, 144L*24*512, 48, 48);
  pack_weights<<<dim3(288, 1, 6), 256, 0, stream>>>(wv, WQKV_P, 768, 768, LSW, 144L*24*512, 96, 48);
  pack_weights<<<dim3(288, 1, 6), 256, 0, stream>>>(wo, WO_P, 768, 768, LSW, 48L*24*512, 0, 48);
  pack_weights<<<dim3(1152, 1, 6), 256, 0, stream>>>(w1, W1_P, 768, 3072, 768L*3072, 192L*24*512, 0, 192);
  pack_weights<<<dim3(1152, 1, 6), 256, 0, stream>>>(w2, W2_P, 3072, 768, 3072L*768, 48L*96*512, 0, 48);
  concat_bias<<<(NLAYER * 2304 + 255) / 256, 256, 0, stream>>>(bq, bk, bv, QKVB);
  embed_kernel<<<NTOK * DM / 1024, 256, 0, stream>>>(ids, emb, X, XB);

  for (int L = 0; L < NLAYER; L++) {
    gemm_pk<128><<<dim3(64, 18), 256, 0, stream>>>(
        XB, WQKV_P + (size_t)L * 144 * 24 * 512, QKVB + L * 2304,
        nullptr, QKVB16, VT, 2304, 768, 0);
    attention_mfma<<<dim3(16, 96), 256, 0, stream>>>(QKVB16, mask, VT, CTXB);
    gemm_pk<64><<<dim3(128, 6), 256, 0, stream>>>(
        CTXB, WO_P + (size_t)L * 48 * 24 * 512, bo + L * 768,
        SCR, nullptr, nullptr, 768, 768, 0);
    ln_residual<<<NTOK, 64, 0, stream>>>(X, SCR, ln1g + L * 768, ln1b + L * 768, X, XB);
    gemm_pk<128><<<dim3(64, 24), 256, 0, stream>>>(
        XB, W1_P + (size_t)L * 192 * 24 * 512, b1 + L * 3072,
        nullptr, H1B, nullptr, 3072, 768, 1);
    gemm_pk<64><<<dim3(128, 6), 256, 0, stream>>>(
        H1B, W2_P + (size_t)L * 48 * 96 * 512, b2 + L * 768,
        SCR, nullptr, nullptr, 768, 3072, 0);
    ln_residual<<<NTOK, 64, 0, stream>>>(X, SCR, ln2g + L * 768, ln2b + L * 768, X, XB);
  }
  classifier_kernel<<<80, 64, 0, stream>>>(X, clsw, clsb, (float*)d_out);
}